// Round 10
// baseline (146.907 us; speedup 1.0000x reference)
//
#include <hip/hip_runtime.h>

#define S_LEN 4096
#define NROWS 16384   // B*S

typedef __attribute__((ext_vector_type(8))) __bf16 bf16x8;
typedef __attribute__((ext_vector_type(8))) unsigned short ushort8;
typedef __attribute__((ext_vector_type(4))) unsigned short ushort4_t;
typedef __attribute__((ext_vector_type(4))) float floatx4;

// Native RTNE f32->bf16 (compiler emits v_cvt_pk_bf16_f32 for pairs).
__device__ __forceinline__ unsigned short f2bf(float f) {
    union { __bf16 h; unsigned short u; } c;
    c.h = (__bf16)f;
    return c.u;
}

__device__ __forceinline__ float fexp2(float x) {
#if __has_builtin(__builtin_amdgcn_exp2f)
    return __builtin_amdgcn_exp2f(x);
#else
    float r; asm("v_exp_f32 %0, %1" : "=v"(r) : "v"(x)); return r;
#endif
}

// ---------------- K0: weights fp32 -> bf16 FRAGMENT-MAJOR buffers (proven).
__global__ __launch_bounds__(256) void convw_kernel(
    const float* __restrict__ Wq, const float* __restrict__ Wk,
    const float* __restrict__ Wv, const float* __restrict__ Wo,
    unsigned short* __restrict__ WqF, unsigned short* __restrict__ WkF,
    unsigned short* __restrict__ WvF, unsigned short* __restrict__ WoF)
{
    int tid = blockIdx.x * 256 + threadIdx.x;   // 0..32767
    {
        const int e = tid & 7, cl = (tid >> 3) & 15, quad = (tid >> 7) & 3;
        const int kc = (tid >> 9) & 15, t = tid >> 13;
        const int n = t * 16 + cl, k = kc * 32 + quad * 8 + e;
        WqF[tid] = f2bf(Wq[k * 64 + n]);
        WkF[tid] = f2bf(Wk[k * 64 + n]);
        WvF[tid] = f2bf(Wv[k * 64 + n]);
    }
    {
        const int e = tid & 7, cl = (tid >> 3) & 15, quad = (tid >> 7) & 3;
        const int h = (tid >> 9) & 1, g = tid >> 10;
        const int n = g * 16 + cl, k = h * 32 + quad * 8 + e;
        WoF[tid] = f2bf(Wo[k * 512 + n]);
    }
}

// ---------------- K1: fused QKV projection, fully coalesced (proven R8).
__global__ __launch_bounds__(192) void qkv_kernel(
    const float* __restrict__ x,
    const unsigned short* __restrict__ WqF, const unsigned short* __restrict__ WkF,
    const unsigned short* __restrict__ WvF,
    const float* __restrict__ bq, const float* __restrict__ bk, const float* __restrict__ bv,
    unsigned short* __restrict__ Qb, unsigned short* __restrict__ KF,
    unsigned short* __restrict__ VF)
{
    __shared__ unsigned short xs[8192];  // 16 KB: x tile bf16, A-frag layout
    const int row0 = blockIdx.x * 16;
    const int tid = threadIdx.x;

    // stage: xs[(k>>5)*512 + ((k>>3)&3)*128 + r*8 + (k&7)] = x[row0+r][k]
    const float* xt = x + (size_t)row0 * 512;
    for (int i = tid; i < 2048; i += 192) {
        float4 v = *(const float4*)(xt + i * 4);
        const int r = i >> 7, k = (i & 127) * 4;
        ushort4_t o;
        o[0] = f2bf(v.x); o[1] = f2bf(v.y); o[2] = f2bf(v.z); o[3] = f2bf(v.w);
        *(ushort4_t*)(xs + (k >> 5) * 512 + ((k >> 3) & 3) * 128 + r * 8 + (k & 7)) = o;
    }
    __syncthreads();

    const int m = tid >> 6;              // wave id: 0=Q, 1=K, 2=V
    const int lane = tid & 63, cl = lane & 15, quad = lane >> 4;
    const unsigned short* WF = (m == 0) ? WqF : (m == 1) ? WkF : WvF;
    const float* bias = (m == 0) ? bq : (m == 1) ? bk : bv;

    floatx4 acc[4];
    #pragma unroll
    for (int t = 0; t < 4; t++) acc[t] = (floatx4){0.f, 0.f, 0.f, 0.f};
    #pragma unroll 2
    for (int kc = 0; kc < 16; kc++) {
        const bf16x8 af = *(const bf16x8*)(const void*)(xs + kc * 512 + lane * 8);
        #pragma unroll
        for (int t = 0; t < 4; t++) {
            const bf16x8 bf = *(const bf16x8*)(const void*)(WF + (size_t)(t * 16 + kc) * 512 + lane * 8);
            acc[t] = __builtin_amdgcn_mfma_f32_16x16x32_bf16(af, bf, acc[t], 0, 0, 0);
        }
    }
    if (m == 0) {
        const float scl = 0.022542110013890054f;   // log2(e)/64
        #pragma unroll
        for (int t = 0; t < 4; t++) {
            const int d = t * 16 + cl;
            const float bd = bias[d];
            #pragma unroll
            for (int r = 0; r < 4; r++)
                Qb[(size_t)(row0 + quad * 4 + r) * 64 + d] = f2bf((acc[t][r] + bd) * scl);
        }
    } else if (m == 1) {
        const int g16 = row0 >> 4;
        #pragma unroll
        for (int t = 0; t < 4; t++) {
            const int d = t * 16 + cl;
            const float bd = bias[d];
            const size_t base = ((size_t)g16 * 8 + (d >> 3)) * 128 + (d & 7);
            #pragma unroll
            for (int r = 0; r < 4; r++)
                KF[base + (quad * 4 + r) * 8] = f2bf(acc[t][r] + bd);
        }
    } else {
        const int b = row0 >> 12, s_base = row0 & 4095;
        #pragma unroll
        for (int t = 0; t < 4; t++) {
            const int d = t * 16 + cl;
            const float bd = bias[d];
            #pragma unroll
            for (int r = 0; r < 4; r++) {
                const int s = s_base + quad * 4 + r;
                const size_t off = (size_t)b * (S_LEN * 64) + (size_t)(s >> 6) * 4096
                                 + ((s >> 5) & 1) * 2048 + t * 512 + cl * 32
                                 + ((s >> 3) & 3) * 8 + (s & 7);
                VF[off] = f2bf(acc[t][r] + bd);
            }
        }
    }
}

// ---------------- K2: causal flash attention (R6/R9 structure).
// Change this round: REMOVED the per-pair __syncthreads. It was an
// L1-locality heuristic only (P-strip LDS is wave-private; no inter-wave
// data). It (1) stalled all 4 waves to the slowest every pair and (2) was
// a compiler scheduling wall blocking next-pair K/V load hoisting. With
// the TA bottleneck fixed (R6), attn is latency-bound: the barrier is the
// remaining pipeline pin.
#define PSTR 152
__global__ __launch_bounds__(256, 2) void attn_kernel(
    const unsigned short* __restrict__ Qb, const unsigned short* __restrict__ Kb,
    const unsigned short* __restrict__ Vt,
    float* __restrict__ Po, float* __restrict__ Pl)
{
    __shared__ float4 shraw[4][304];
    const int bid = blockIdx.x;              // 0..1023
    const int pair = bid >> 2, h = bid & 3;
    const int a = 63 - (pair >> 2);
    const int b = pair & 3;
    const int q0 = a * 64;
    const int nkt = a + 1;
    const int kt0 = (h * nkt) >> 2;
    const int kt1 = ((h + 1) * nkt) >> 2;
    const int tid = threadIdx.x;
    const int w = tid >> 6, lane = tid & 63, cl = lane & 15, quad = lane >> 4;

    const size_t qrow = (size_t)b * S_LEN + q0 + w * 16 + cl;
    const bf16x8 aq0 = *(const bf16x8*)(const void*)(Qb + qrow * 64 + quad * 8);
    const bf16x8 aq1 = *(const bf16x8*)(const void*)(Qb + qrow * 64 + 32 + quad * 8);
    const unsigned short* kbb = Kb + (size_t)b * S_LEN * 64;
    const unsigned short* vbb = Vt + (size_t)b * S_LEN * 64;
    const int qm = q0 + w * 16 + quad * 4;

    float lrow[4];
    floatx4 Oacc[4];
    #pragma unroll
    for (int r = 0; r < 4; r++) lrow[r] = 0.f;
    #pragma unroll
    for (int u = 0; u < 4; u++) Oacc[u] = (floatx4){0.f, 0.f, 0.f, 0.f};

    unsigned short* Pw = (unsigned short*)&shraw[w][0];

    int jt = kt0;
    for (; jt + 1 < kt1; jt += 2) {
        float z[8][4];
        bf16x8 vf[8][2];
        {
            bf16x8 kf[4][2];
            #pragma unroll
            for (int t = 0; t < 4; t++) {
                const unsigned short* kp = kbb + ((size_t)(jt * 4 + t) * 8 + quad) * 128 + cl * 8;
                kf[t][0] = *(const bf16x8*)(const void*)kp;
                kf[t][1] = *(const bf16x8*)(const void*)(kp + 512);
            }
            #pragma unroll
            for (int t = 0; t < 4; t++) {
                floatx4 acc = (floatx4){0.f, 0.f, 0.f, 0.f};
                acc = __builtin_amdgcn_mfma_f32_16x16x32_bf16(aq0, kf[t][0], acc, 0, 0, 0);
                acc = __builtin_amdgcn_mfma_f32_16x16x32_bf16(aq1, kf[t][1], acc, 0, 0, 0);
                #pragma unroll
                for (int r = 0; r < 4; r++) z[t][r] = acc[r];
            }
        }
        #pragma unroll
        for (int u = 0; u < 4; u++) {
            const unsigned short* vp = vbb + (size_t)jt * 4096 + u * 512 + cl * 32 + quad * 8;
            vf[u][0] = *(const bf16x8*)(const void*)vp;
            vf[u][1] = *(const bf16x8*)(const void*)(vp + 2048);
        }
        {
            bf16x8 kf[4][2];
            #pragma unroll
            for (int t = 0; t < 4; t++) {
                const unsigned short* kp = kbb + ((size_t)((jt + 1) * 4 + t) * 8 + quad) * 128 + cl * 8;
                kf[t][0] = *(const bf16x8*)(const void*)kp;
                kf[t][1] = *(const bf16x8*)(const void*)(kp + 512);
            }
            #pragma unroll
            for (int t = 0; t < 4; t++) {
                floatx4 acc = (floatx4){0.f, 0.f, 0.f, 0.f};
                acc = __builtin_amdgcn_mfma_f32_16x16x32_bf16(aq0, kf[t][0], acc, 0, 0, 0);
                acc = __builtin_amdgcn_mfma_f32_16x16x32_bf16(aq1, kf[t][1], acc, 0, 0, 0);
                #pragma unroll
                for (int r = 0; r < 4; r++) z[4 + t][r] = acc[r];
            }
        }
        #pragma unroll
        for (int u = 0; u < 4; u++) {
            const unsigned short* vp = vbb + (size_t)(jt + 1) * 4096 + u * 512 + cl * 32 + quad * 8;
            vf[4 + u][0] = *(const bf16x8*)(const void*)vp;
            vf[4 + u][1] = *(const bf16x8*)(const void*)(vp + 2048);
        }
        if (jt + 1 == nkt - 1) {
            const int j0b = (jt + 1) * 64;
            #pragma unroll
            for (int t = 0; t < 4; t++)
                #pragma unroll
                for (int r = 0; r < 4; r++)
                    if (j0b + t * 16 + cl > qm + r) z[4 + t][r] = -1e30f;
        }
        #pragma unroll
        for (int t = 0; t < 8; t++)
            #pragma unroll
            for (int r = 0; r < 4; r++) z[t][r] = fexp2(z[t][r]);
        #pragma unroll
        for (int r = 0; r < 4; r++)
            lrow[r] += ((z[0][r] + z[1][r]) + (z[2][r] + z[3][r]))
                     + ((z[4][r] + z[5][r]) + (z[6][r] + z[7][r]));
        #pragma unroll
        for (int t = 0; t < 8; t++)
            #pragma unroll
            for (int r = 0; r < 4; r++)
                Pw[(quad * 4 + r) * PSTR + t * 16 + cl] = f2bf(z[t][r]);
        bf16x8 ap0 = *(const bf16x8*)(const void*)(Pw + cl * PSTR + quad * 8);
        bf16x8 ap1 = *(const bf16x8*)(const void*)(Pw + cl * PSTR + 32 + quad * 8);
        bf16x8 ap2 = *(const bf16x8*)(const void*)(Pw + cl * PSTR + 64 + quad * 8);
        bf16x8 ap3 = *(const bf16x8*)(const void*)(Pw + cl * PSTR + 96 + quad * 8);
        #pragma unroll
        for (int u = 0; u < 4; u++) {
            Oacc[u] = __builtin_amdgcn_mfma_f32_16x16x32_bf16(ap0, vf[u][0], Oacc[u], 0, 0, 0);
            Oacc[u] = __builtin_amdgcn_mfma_f32_16x16x32_bf16(ap1, vf[u][1], Oacc[u], 0, 0, 0);
            Oacc[u] = __builtin_amdgcn_mfma_f32_16x16x32_bf16(ap2, vf[4 + u][0], Oacc[u], 0, 0, 0);
            Oacc[u] = __builtin_amdgcn_mfma_f32_16x16x32_bf16(ap3, vf[4 + u][1], Oacc[u], 0, 0, 0);
        }
    }
    if (jt < kt1) {
        bf16x8 kf[4][2], vf[4][2];
        #pragma unroll
        for (int t = 0; t < 4; t++) {
            const unsigned short* kp = kbb + ((size_t)(jt * 4 + t) * 8 + quad) * 128 + cl * 8;
            kf[t][0] = *(const bf16x8*)(const void*)kp;
            kf[t][1] = *(const bf16x8*)(const void*)(kp + 512);
        }
        #pragma unroll
        for (int u = 0; u < 4; u++) {
            const unsigned short* vp = vbb + (size_t)jt * 4096 + u * 512 + cl * 32 + quad * 8;
            vf[u][0] = *(const bf16x8*)(const void*)vp;
            vf[u][1] = *(const bf16x8*)(const void*)(vp + 2048);
        }
        float z[4][4];
        #pragma unroll
        for (int t = 0; t < 4; t++) {
            floatx4 acc = (floatx4){0.f, 0.f, 0.f, 0.f};
            acc = __builtin_amdgcn_mfma_f32_16x16x32_bf16(aq0, kf[t][0], acc, 0, 0, 0);
            acc = __builtin_amdgcn_mfma_f32_16x16x32_bf16(aq1, kf[t][1], acc, 0, 0, 0);
            #pragma unroll
            for (int r = 0; r < 4; r++) z[t][r] = acc[r];
        }
        if (jt == nkt - 1) {
            const int j0 = jt * 64;
            #pragma unroll
            for (int t = 0; t < 4; t++)
                #pragma unroll
                for (int r = 0; r < 4; r++)
                    if (j0 + t * 16 + cl > qm + r) z[t][r] = -1e30f;
        }
        #pragma unroll
        for (int t = 0; t < 4; t++)
            #pragma unroll
            for (int r = 0; r < 4; r++) z[t][r] = fexp2(z[t][r]);
        #pragma unroll
        for (int r = 0; r < 4; r++)
            lrow[r] += ((z[0][r] + z[1][r]) + (z[2][r] + z[3][r]));
        #pragma unroll
        for (int t = 0; t < 4; t++)
            #pragma unroll
            for (int r = 0; r < 4; r++)
                Pw[(quad * 4 + r) * PSTR + t * 16 + cl] = f2bf(z[t][r]);
        bf16x8 ap0 = *(const bf16x8*)(const void*)(Pw + cl * PSTR + quad * 8);
        bf16x8 ap1 = *(const bf16x8*)(const void*)(Pw + cl * PSTR + 32 + quad * 8);
        #pragma unroll
        for (int u = 0; u < 4; u++) {
            Oacc[u] = __builtin_amdgcn_mfma_f32_16x16x32_bf16(ap0, vf[u][0], Oacc[u], 0, 0, 0);
            Oacc[u] = __builtin_amdgcn_mfma_f32_16x16x32_bf16(ap1, vf[u][1], Oacc[u], 0, 0, 0);
        }
    }
    #pragma unroll
    for (int r = 0; r < 4; r++) {
        float s = lrow[r];
        s += __shfl_xor(s, 1, 64);
        s += __shfl_xor(s, 2, 64);
        s += __shfl_xor(s, 4, 64);
        s += __shfl_xor(s, 8, 64);
        lrow[r] = s;
    }
    // write unnormalized partial in A-fragment-major f32 (for fused oproj)
    {
        float* pob = Po + (size_t)bid * 4096 + w * 1024;
        #pragma unroll
        for (int u = 0; u < 4; u++) {
            const int base = (u >> 1) * 512
                           + (((u & 1) * 2 + (cl >> 3)) * 16 + quad * 4) * 8 + (cl & 7);
            #pragma unroll
            for (int r = 0; r < 4; r++)
                pob[base + r * 8] = Oacc[u][r];
        }
        if (cl == 0) {
            #pragma unroll
            for (int r = 0; r < 4; r++)
                Pl[(size_t)bid * 64 + w * 16 + quad * 4 + r] = lrow[r];
        }
    }
}

// ---------------- K3: FUSED merge + out-projection (proven R9).
__global__ __launch_bounds__(256) void oproj_kernel(
    const float* __restrict__ Po, const float* __restrict__ Pl,
    const unsigned short* __restrict__ WoF,
    const float* __restrict__ bo, float* __restrict__ out)
{
    const int blk = blockIdx.x;              // 0..1023, 16 rows each
    const int row0 = blk * 16;
    const int b = row0 >> 12, s0 = row0 & 4095;
    const int a = s0 >> 6, g16 = (s0 >> 4) & 3;
    const int pair = (63 - a) * 4 + b;       // attn pair for this (a,b)
    const int tid = threadIdx.x;
    const int w = tid >> 6, lane = tid & 63, cl = lane & 15, quad = lane >> 4;

    float s0v[8], s1v[8];
    #pragma unroll
    for (int e = 0; e < 8; e++) { s0v[e] = 0.f; s1v[e] = 0.f; }
    #pragma unroll
    for (int h = 0; h < 4; h++) {
        const float* p = Po + ((size_t)(pair * 4 + h) * 4 + g16) * 1024 + lane * 8;
        #pragma unroll
        for (int e = 0; e < 8; e++) s0v[e] += p[e];
        #pragma unroll
        for (int e = 0; e < 8; e++) s1v[e] += p[512 + e];
    }
    float L = 0.f;
    #pragma unroll
    for (int h = 0; h < 4; h++)
        L += Pl[(size_t)(pair * 4 + h) * 64 + g16 * 16 + cl];
    const float invL = 1.0f / L;             // row for this lane = cl

    bf16x8 a0, a1;
    #pragma unroll
    for (int e = 0; e < 8; e++) {
        a0[e] = (__bf16)(s0v[e] * invL);
        a1[e] = (__bf16)(s1v[e] * invL);
    }

    #pragma unroll 2
    for (int i = 0; i < 8; i++) {
        const int g = w * 8 + i;
        const int n = g * 16 + cl;
        bf16x8 b0 = *(const bf16x8*)(const void*)(WoF + (size_t)(g * 2 + 0) * 512 + lane * 8);
        bf16x8 b1 = *(const bf16x8*)(const void*)(WoF + (size_t)(g * 2 + 1) * 512 + lane * 8);
        floatx4 acc = (floatx4){0.f, 0.f, 0.f, 0.f};
        acc = __builtin_amdgcn_mfma_f32_16x16x32_bf16(a0, b0, acc, 0, 0, 0);
        acc = __builtin_amdgcn_mfma_f32_16x16x32_bf16(a1, b1, acc, 0, 0, 0);
        const float bod = bo[n];
        #pragma unroll
        for (int r = 0; r < 4; r++)
            out[(size_t)(row0 + quad * 4 + r) * 512 + n] = acc[r] + bod;
    }
}

extern "C" void kernel_launch(void* const* d_in, const int* in_sizes, int n_in,
                              void* d_out, int out_size, void* d_ws, size_t ws_size,
                              hipStream_t stream) {
    const float* x  = (const float*)d_in[0];
    const float* Wq = (const float*)d_in[1];
    const float* bq = (const float*)d_in[2];
    const float* Wk = (const float*)d_in[3];
    const float* bk = (const float*)d_in[4];
    const float* Wv = (const float*)d_in[5];
    const float* bv = (const float*)d_in[6];
    const float* Wo = (const float*)d_in[7];
    const float* bo = (const float*)d_in[8];
    float* out = (float*)d_out;

    unsigned short* Qb  = (unsigned short*)d_ws;               // 2 MB
    unsigned short* KF  = Qb + (size_t)NROWS * 64;             // 2 MB (fragment-major)
    unsigned short* VF  = KF + (size_t)NROWS * 64;             // 2 MB (fragment-major)
    unsigned short* WqF = VF + (size_t)NROWS * 64;             // 64 KB each
    unsigned short* WkF = WqF + 512 * 64;
    unsigned short* WvF = WkF + 512 * 64;
    unsigned short* WoF = WvF + 512 * 64;
    float* Pl = (float*)(WoF + 512 * 64);                      // 1024*64 f32 = 256 KB
    float* Po = Pl + (size_t)1024 * 64;                        // 1024*4096 f32 = 16 MB

    convw_kernel<<<128, 256, 0, stream>>>(Wq, Wk, Wv, Wo, WqF, WkF, WvF, WoF);
    qkv_kernel<<<1024, 192, 0, stream>>>(x, WqF, WkF, WvF, bq, bk, bv, Qb, KF, VF);
    attn_kernel<<<1024, 256, 0, stream>>>(Qb, KF, VF, Po, Pl);
    oproj_kernel<<<NROWS / 16, 256, 0, stream>>>(Po, Pl, WoF, bo, out);
}